// Round 4
// baseline (397.889 us; speedup 1.0000x reference)
//
#include <hip/hip_runtime.h>
#include <hip/hip_bf16.h>
#include <stdint.h>

#define NN   100000
#define NE   1600000
#define KIN  256
#define FOUT 128

typedef __attribute__((ext_vector_type(8))) short short8;
typedef __attribute__((ext_vector_type(4))) float f32x4;
typedef __attribute__((ext_vector_type(2))) float f32x2;

static __device__ __forceinline__ unsigned short f2bf(float f) {
  unsigned int u = __float_as_uint(f);
  u += 0x7fffu + ((u >> 16) & 1u);   // RNE (inputs finite)
  return (unsigned short)(u >> 16);
}

static __device__ __forceinline__ short8 pack8(float4 u, float4 v) {
  short8 r;
  r[0] = (short)f2bf(u.x); r[1] = (short)f2bf(u.y);
  r[2] = (short)f2bf(u.z); r[3] = (short)f2bf(u.w);
  r[4] = (short)f2bf(v.x); r[5] = (short)f2bf(v.y);
  r[6] = (short)f2bf(v.z); r[7] = (short)f2bf(v.w);
  return r;
}

// ---------------------------------------------------------------------------
// 1) Fused setup: blocks [0,6250) build row_ptr (linear edge scan);
//    blocks [6250,6378) transpose-convert W -> wt[which][n][k] bf16.
__global__ __launch_bounds__(256) void setup(const int* __restrict__ rows0,
                                             const int* __restrict__ rows1,
                                             const float* __restrict__ W0,
                                             const float* __restrict__ W1,
                                             int* __restrict__ rp0,
                                             int* __restrict__ rp1,
                                             unsigned short* __restrict__ wt) {
  const int which = blockIdx.y;
  const int bx = blockIdx.x;
  if (bx < 6250) {
    const int e = bx * 256 + threadIdx.x;              // 6250*256 == NE
    const int* rows = which ? rows1 : rows0;
    int* rp = which ? rp1 : rp0;
    int r1 = rows[e];
    int r2 = (e + 1 < NE) ? rows[e + 1] : NN;
    if (e == 0)
      for (int r = 0; r <= r1; ++r) rp[r] = 0;
    for (int r = r1 + 1; r <= r2; ++r) rp[r] = e + 1;
  } else {
    const int n = bx - 6250;                           // 0..127
    const int k = threadIdx.x;                         // 0..255
    const float* W = which ? W1 : W0;
    wt[(size_t)which * (FOUT * KIN) + n * KIN + k] = f2bf(W[k * FOUT + n]);
  }
}

// ---------------------------------------------------------------------------
// 2) GEMM, single pass over x: block = 32 rows (3125*32 == NN exactly, no
//    masks). 4 waves = {which} x {64-col half}; all waves share A rows (L1).
//    Wave tile 32x64: acc[2][4] = 32 VGPR; unroll 2 caps pressure.
//    Epilogue: wave-private LDS stage -> coalesced 16B stores.
__global__ __launch_bounds__(256) void gemm_mfma(const float* __restrict__ x,
                                                 const unsigned short* __restrict__ wt,
                                                 unsigned short* __restrict__ h) {
  __shared__ __align__(16) unsigned short tile[4][32 * 64];   // 16 KB

  const int tid  = threadIdx.x;
  const int lane = tid & 63;
  const int wv   = tid >> 6;
  const int which = wv >> 1;
  const int colbase = (wv & 1) * 64;
  const int rowbase = blockIdx.x * 32;
  const int m    = lane & 15;
  const int quad = lane >> 4;

  const unsigned short* w = wt + (size_t)which * (FOUT * KIN);
  unsigned short* hh = h + (size_t)which * NN * FOUT;

  const float* ap0 = x + (size_t)(rowbase + m) * KIN + quad * 8;
  const float* ap1 = x + (size_t)(rowbase + 16 + m) * KIN + quad * 8;
  const unsigned short* b0p = w + (size_t)(colbase + 0  + m) * KIN + quad * 8;
  const unsigned short* b1p = w + (size_t)(colbase + 16 + m) * KIN + quad * 8;
  const unsigned short* b2p = w + (size_t)(colbase + 32 + m) * KIN + quad * 8;
  const unsigned short* b3p = w + (size_t)(colbase + 48 + m) * KIN + quad * 8;

  f32x4 acc[2][4];
#pragma unroll
  for (int i = 0; i < 2; ++i)
#pragma unroll
    for (int j = 0; j < 4; ++j)
      acc[i][j] = (f32x4){0.f, 0.f, 0.f, 0.f};

#pragma unroll 2
  for (int ko = 0; ko < KIN; ko += 32) {
    float4 a0lo = *(const float4*)(ap0 + ko);
    float4 a0hi = *(const float4*)(ap0 + ko + 4);
    float4 a1lo = *(const float4*)(ap1 + ko);
    float4 a1hi = *(const float4*)(ap1 + ko + 4);
    short8 b0 = *(const short8*)(b0p + ko);
    short8 b1 = *(const short8*)(b1p + ko);
    short8 b2 = *(const short8*)(b2p + ko);
    short8 b3 = *(const short8*)(b3p + ko);
    short8 a0 = pack8(a0lo, a0hi);
    short8 a1 = pack8(a1lo, a1hi);
    acc[0][0] = __builtin_amdgcn_mfma_f32_16x16x32_bf16(a0, b0, acc[0][0], 0, 0, 0);
    acc[0][1] = __builtin_amdgcn_mfma_f32_16x16x32_bf16(a0, b1, acc[0][1], 0, 0, 0);
    acc[0][2] = __builtin_amdgcn_mfma_f32_16x16x32_bf16(a0, b2, acc[0][2], 0, 0, 0);
    acc[0][3] = __builtin_amdgcn_mfma_f32_16x16x32_bf16(a0, b3, acc[0][3], 0, 0, 0);
    acc[1][0] = __builtin_amdgcn_mfma_f32_16x16x32_bf16(a1, b0, acc[1][0], 0, 0, 0);
    acc[1][1] = __builtin_amdgcn_mfma_f32_16x16x32_bf16(a1, b1, acc[1][1], 0, 0, 0);
    acc[1][2] = __builtin_amdgcn_mfma_f32_16x16x32_bf16(a1, b2, acc[1][2], 0, 0, 0);
    acc[1][3] = __builtin_amdgcn_mfma_f32_16x16x32_bf16(a1, b3, acc[1][3], 0, 0, 0);
  }

  // D layout: col = lane&15 (=m), row = quad*4 + reg  [m89/m91 verified]
#pragma unroll
  for (int i = 0; i < 2; ++i)
#pragma unroll
    for (int reg = 0; reg < 4; ++reg)
#pragma unroll
      for (int j = 0; j < 4; ++j)
        tile[wv][(i * 16 + quad * 4 + reg) * 64 + j * 16 + m] = f2bf(acc[i][j][reg]);

#pragma unroll
  for (int p = 0; p < 4; ++p) {
    int row = p * 8 + (lane >> 3);
    int colb = (lane & 7) * 8;
    uint4 v = *(const uint4*)&tile[wv][row * 64 + colb];
    *(uint4*)&hh[(size_t)(rowbase + row) * FOUT + colbase + colb] = v;
  }
}

// ---------------------------------------------------------------------------
// 3) Fused SpMM + relu, continuously software-pipelined: ping-pong register
//    buffers keep 8-16 gathers in flight across batch boundaries (R3 drained
//    to 0 each iteration -> one miss latency per 16 edges).
static __device__ __forceinline__ void issue8(const int* __restrict__ cols, int i,
                                              const unsigned short* __restrict__ hsrc,
                                              int fo, unsigned* g) {
#pragma unroll
  for (int u = 0; u < 8; ++u) {
    int c = cols[i + u];                        // uniform -> s_load
    g[u] = *(const unsigned*)(hsrc + (size_t)c * FOUT + fo);
  }
}

static __device__ __forceinline__ void consume8(const float* __restrict__ vals, int i,
                                                const unsigned* g, float& sx, float& sy) {
#pragma unroll
  for (int u = 0; u < 8; ++u) {
    float v = vals[i + u];                      // uniform -> s_load
    sx += v * __uint_as_float(g[u] << 16);
    sy += v * __uint_as_float(g[u] & 0xffff0000u);
  }
}

static __device__ __forceinline__ void tail_spmm(const int* __restrict__ cols,
                                                 const float* __restrict__ vals,
                                                 const unsigned short* __restrict__ hsrc,
                                                 int i, int e, int fo,
                                                 float& sx, float& sy) {
  for (; i + 4 <= e; i += 4) {
    int c0 = cols[i], c1 = cols[i + 1], c2 = cols[i + 2], c3 = cols[i + 3];
    unsigned g0 = *(const unsigned*)(hsrc + (size_t)c0 * FOUT + fo);
    unsigned g1 = *(const unsigned*)(hsrc + (size_t)c1 * FOUT + fo);
    unsigned g2 = *(const unsigned*)(hsrc + (size_t)c2 * FOUT + fo);
    unsigned g3 = *(const unsigned*)(hsrc + (size_t)c3 * FOUT + fo);
    float v0 = vals[i], v1 = vals[i + 1], v2 = vals[i + 2], v3 = vals[i + 3];
    sx += v0 * __uint_as_float(g0 << 16);
    sy += v0 * __uint_as_float(g0 & 0xffff0000u);
    sx += v1 * __uint_as_float(g1 << 16);
    sy += v1 * __uint_as_float(g1 & 0xffff0000u);
    sx += v2 * __uint_as_float(g2 << 16);
    sy += v2 * __uint_as_float(g2 & 0xffff0000u);
    sx += v3 * __uint_as_float(g3 << 16);
    sy += v3 * __uint_as_float(g3 & 0xffff0000u);
  }
  for (; i < e; ++i) {
    int c = cols[i];
    float v = vals[i];
    unsigned g = *(const unsigned*)(hsrc + (size_t)c * FOUT + fo);
    sx += v * __uint_as_float(g << 16);
    sy += v * __uint_as_float(g & 0xffff0000u);
  }
}

static __device__ __forceinline__ void spmm_pipe(const int* __restrict__ cols,
                                                 const float* __restrict__ vals,
                                                 const unsigned short* __restrict__ hsrc,
                                                 const int* __restrict__ rp,
                                                 int r, int fo,
                                                 float& sx, float& sy) {
  int i = __builtin_amdgcn_readfirstlane(rp[r]);
  int e = __builtin_amdgcn_readfirstlane(rp[r + 1]);
  if (i + 8 <= e) {
    unsigned gA[8], gB[8];
    issue8(cols, i, hsrc, fo, gA);              // prime: gA = batch(i)
    for (;;) {
      if (i + 16 <= e) {                        // next batch exists
        issue8(cols, i + 8, hsrc, fo, gB);      // keep 16 in flight
        consume8(vals, i, gA, sx, sy);
        i += 8;
      } else {
        consume8(vals, i, gA, sx, sy);
        i += 8;
        break;
      }
      if (i + 16 <= e) {
        issue8(cols, i + 8, hsrc, fo, gA);
        consume8(vals, i, gB, sx, sy);
        i += 8;
      } else {
        consume8(vals, i, gB, sx, sy);
        i += 8;
        break;
      }
    }
  }
  tail_spmm(cols, vals, hsrc, i, e, fo, sx, sy);
}

__global__ __launch_bounds__(256) void spmm_relu(
    const int* __restrict__ rp0, const int* __restrict__ cols0, const float* __restrict__ vals0,
    const int* __restrict__ rp1, const int* __restrict__ cols1, const float* __restrict__ vals1,
    const unsigned short* __restrict__ h, float* __restrict__ out) {
  const int lane = threadIdx.x & 63;
  int r = blockIdx.x * 4 + (threadIdx.x >> 6);   // 25000*4 == NN exactly
  r = __builtin_amdgcn_readfirstlane(r);
  const int fo = lane * 2;

  const unsigned short* h0 = h;
  const unsigned short* h1 = h + (size_t)NN * FOUT;

  float sx = 0.f, sy = 0.f;
  spmm_pipe(cols0, vals0, h0, rp0, r, fo, sx, sy);
  spmm_pipe(cols1, vals1, h1, rp1, r, fo, sx, sy);

  f32x2 o;
  o.x = sx > 0.f ? sx : 0.f;
  o.y = sy > 0.f ? sy : 0.f;
  __builtin_nontemporal_store(o, (f32x2*)(out + (size_t)r * FOUT + fo));
}

// ---------------------------------------------------------------------------
extern "C" void kernel_launch(void* const* d_in, const int* in_sizes, int n_in,
                              void* d_out, int out_size, void* d_ws, size_t ws_size,
                              hipStream_t stream) {
  const float* x     = (const float*)d_in[0];
  const int*   rows0 = (const int*)d_in[1];
  const int*   cols0 = (const int*)d_in[2];
  const float* vals0 = (const float*)d_in[3];
  const int*   rows1 = (const int*)d_in[4];
  const int*   cols1 = (const int*)d_in[5];
  const float* vals1 = (const float*)d_in[6];
  const float* W0    = (const float*)d_in[7];
  const float* W1    = (const float*)d_in[8];
  float* out = (float*)d_out;

  // ws layout (16B aligned):
  //   wt  : 2*128*256 bf16 =    131,072 B @ 0
  //   h   : 2*NN*128 bf16  = 51,200,000 B @ 131,072
  //   rp0 : (NN+1) i32     @ 51,331,072
  //   rp1 : (NN+1) i32     @ 51,731,136
  char* ws = (char*)d_ws;
  unsigned short* wt = (unsigned short*)(ws);
  unsigned short* h  = (unsigned short*)(ws + 131072);
  int* rp0 = (int*)(ws + 51331072);
  int* rp1 = (int*)(ws + 51731136);

  setup<<<dim3(6378, 2), 256, 0, stream>>>(rows0, rows1, W0, W1, rp0, rp1, wt);
  gemm_mfma<<<NN / 32, 256, 0, stream>>>(x, wt, h);
  spmm_relu<<<NN / 4, 256, 0, stream>>>(rp0, cols0, vals0, rp1, cols1, vals1, h, out);
}